// Round 1
// baseline (4457.975 us; speedup 1.0000x reference)
//
#include <hip/hip_runtime.h>

// Problem constants (B,H,L,D) = (2,16,2048,128), all fp32.
constexpr int Bc = 2, Hc = 16, Lc = 2048, Dc = 128;
constexpr int BHc = Bc * Hc;                       // 32
constexpr float RSCALE = 0.08838834764831845f;     // 1/sqrt(128)
constexpr size_t OUT_ELEMS = (size_t)BHc * Lc * Dc; // 8388608, start of attn_weight region

// ---------------------------------------------------------------------------
// K1: raw scores  S[bh][q][k] = (Q·K) * (1 + A*wA + D*wD) * RSCALE
// 128x128 tile per block, BK=32 LDS chunks, 8x8 register tile per thread.
// ---------------------------------------------------------------------------
__global__ __launch_bounds__(256)
void k_scores(const float* __restrict__ Qg, const float* __restrict__ Kg,
              const float* __restrict__ Ag, const float* __restrict__ Dg,
              const float* __restrict__ wAg, const float* __restrict__ wDg,
              float* __restrict__ Sg)
{
    __shared__ float Qs[128][36];   // pad 32->36: lane rows consecutive => <=2-way conflicts
    __shared__ float Ks[128][36];

    const int kt = blockIdx.x, qt = blockIdx.y, bh = blockIdx.z;
    const int b = bh >> 4, h = bh & 15;
    const int q0 = qt * 128, k0 = kt * 128;
    const int tid = threadIdx.x;
    const int tx = tid & 15, ty = tid >> 4;

    const float wa = wAg[h], wd = wDg[h];
    const float* Qb = Qg + ((size_t)bh * Lc + q0) * Dc;
    const float* Kb = Kg + ((size_t)bh * Lc + k0) * Dc;

    float acc[8][8];
#pragma unroll
    for (int i = 0; i < 8; i++)
#pragma unroll
        for (int j = 0; j < 8; j++) acc[i][j] = 0.0f;

    for (int c = 0; c < 4; c++) {           // D chunks of 32
        // Load 128x32 of Q and K (1024 float4 each; 4 per thread), coalesced.
#pragma unroll
        for (int i = 0; i < 4; i++) {
            int idx = tid + 256 * i;        // 0..1023
            int row = idx >> 3;             // 0..127
            int c4  = idx & 7;              // float4 within 32-float chunk
            float4 qv = *(const float4*)(Qb + (size_t)row * Dc + c * 32 + c4 * 4);
            float4 kv = *(const float4*)(Kb + (size_t)row * Dc + c * 32 + c4 * 4);
            *(float4*)&Qs[row][c4 * 4] = qv;
            *(float4*)&Ks[row][c4 * 4] = kv;
        }
        __syncthreads();

#pragma unroll
        for (int d4 = 0; d4 < 8; d4++) {    // 8 steps of 4 d-values
            float4 a[8], bbv[8];
#pragma unroll
            for (int i = 0; i < 8; i++) a[i]   = *(const float4*)&Qs[ty + 16 * i][d4 * 4];
#pragma unroll
            for (int j = 0; j < 8; j++) bbv[j] = *(const float4*)&Ks[tx + 16 * j][d4 * 4];
#pragma unroll
            for (int i = 0; i < 8; i++)
#pragma unroll
                for (int j = 0; j < 8; j++)
                    acc[i][j] += a[i].x * bbv[j].x + a[i].y * bbv[j].y
                               + a[i].z * bbv[j].z + a[i].w * bbv[j].w;
        }
        __syncthreads();
    }

    // Epilogue: multiplier + scale, write raw scores.
    const float* Arow = Ag + (size_t)b * Lc * Lc;
    const float* Drow = Dg + (size_t)b * Lc * Lc;
    float* Srow = Sg + (size_t)bh * Lc * Lc;
#pragma unroll
    for (int i = 0; i < 8; i++) {
        int q = q0 + ty + 16 * i;
        size_t ro = (size_t)q * Lc + k0;
#pragma unroll
        for (int j = 0; j < 8; j++) {
            int k = tx + 16 * j;
            float av = Arow[ro + k];
            float dv = Drow[ro + k];
            float mult = 1.0f + av * wa + dv * wd;
            Srow[ro + k] = acc[i][j] * mult * RSCALE;
        }
    }
}

// ---------------------------------------------------------------------------
// K2: in-place row softmax over k (2048 per row). One block per row.
// exp kept in registers => one read + one write of the 537MB matrix.
// ---------------------------------------------------------------------------
__global__ __launch_bounds__(256)
void k_softmax(float* __restrict__ Sg)
{
    __shared__ float red[8];
    const size_t row = blockIdx.x;
    float* Sr = Sg + row * (size_t)Lc;
    const int tid = threadIdx.x;
    const int w = tid >> 6;

    float4 v0 = *(const float4*)(Sr + tid * 4);
    float4 v1 = *(const float4*)(Sr + 1024 + tid * 4);

    float m = fmaxf(fmaxf(fmaxf(v0.x, v0.y), fmaxf(v0.z, v0.w)),
                    fmaxf(fmaxf(v1.x, v1.y), fmaxf(v1.z, v1.w)));
#pragma unroll
    for (int off = 32; off; off >>= 1) m = fmaxf(m, __shfl_xor(m, off));
    if ((tid & 63) == 0) red[w] = m;
    __syncthreads();
    m = fmaxf(fmaxf(red[0], red[1]), fmaxf(red[2], red[3]));

    float4 e0, e1;
    e0.x = __expf(v0.x - m); e0.y = __expf(v0.y - m);
    e0.z = __expf(v0.z - m); e0.w = __expf(v0.w - m);
    e1.x = __expf(v1.x - m); e1.y = __expf(v1.y - m);
    e1.z = __expf(v1.z - m); e1.w = __expf(v1.w - m);

    float s = e0.x + e0.y + e0.z + e0.w + e1.x + e1.y + e1.z + e1.w;
#pragma unroll
    for (int off = 32; off; off >>= 1) s += __shfl_xor(s, off);
    if ((tid & 63) == 0) red[4 + w] = s;
    __syncthreads();
    float l = red[4] + red[5] + red[6] + red[7];
    float rinv = 1.0f / l;

    e0.x *= rinv; e0.y *= rinv; e0.z *= rinv; e0.w *= rinv;
    e1.x *= rinv; e1.y *= rinv; e1.z *= rinv; e1.w *= rinv;
    *(float4*)(Sr + tid * 4) = e0;
    *(float4*)(Sr + 1024 + tid * 4) = e1;
}

// ---------------------------------------------------------------------------
// K3: out = P · V.  128 q-rows x 128 d per block, BK=32, 8x8 per thread.
// ---------------------------------------------------------------------------
__global__ __launch_bounds__(256)
void k_pv(const float* __restrict__ Pg, const float* __restrict__ Vg,
          float* __restrict__ Og)
{
    __shared__ float Ps[128][36];
    __shared__ float Vs[32][132];

    const int qt = blockIdx.x, bh = blockIdx.y;
    const int q0 = qt * 128;
    const int tid = threadIdx.x;
    const int tx = tid & 15, ty = tid >> 4;

    const float* Pb = Pg + ((size_t)bh * Lc + q0) * (size_t)Lc;
    const float* Vb = Vg + (size_t)bh * Lc * Dc;

    float acc[8][8];
#pragma unroll
    for (int i = 0; i < 8; i++)
#pragma unroll
        for (int j = 0; j < 8; j++) acc[i][j] = 0.0f;

    for (int k0 = 0; k0 < Lc; k0 += 32) {
#pragma unroll
        for (int i = 0; i < 4; i++) {
            int idx = tid + 256 * i;            // 0..1023
            int rowp = idx >> 3, c4p = idx & 7; // P: 128 rows x 8 float4
            *(float4*)&Ps[rowp][c4p * 4] =
                *(const float4*)(Pb + (size_t)rowp * Lc + k0 + c4p * 4);
            int rowv = idx >> 5, c4v = idx & 31; // V: 32 rows x 32 float4
            *(float4*)&Vs[rowv][c4v * 4] =
                *(const float4*)(Vb + (size_t)(k0 + rowv) * Dc + c4v * 4);
        }
        __syncthreads();

#pragma unroll
        for (int kk4 = 0; kk4 < 8; kk4++) {
            float4 a[8];
#pragma unroll
            for (int i = 0; i < 8; i++) a[i] = *(const float4*)&Ps[ty + 16 * i][kk4 * 4];
#pragma unroll
            for (int cc = 0; cc < 4; cc++) {
                int kk = kk4 * 4 + cc;
                float4 b0 = *(const float4*)&Vs[kk][tx * 4];
                float4 b1 = *(const float4*)&Vs[kk][64 + tx * 4];
#pragma unroll
                for (int i = 0; i < 8; i++) {
                    float av = (cc == 0) ? a[i].x : (cc == 1) ? a[i].y
                             : (cc == 2) ? a[i].z : a[i].w;
                    acc[i][0] += av * b0.x; acc[i][1] += av * b0.y;
                    acc[i][2] += av * b0.z; acc[i][3] += av * b0.w;
                    acc[i][4] += av * b1.x; acc[i][5] += av * b1.y;
                    acc[i][6] += av * b1.z; acc[i][7] += av * b1.w;
                }
            }
        }
        __syncthreads();
    }

#pragma unroll
    for (int i = 0; i < 8; i++) {
        int q = q0 + ty + 16 * i;
        float* Or = Og + ((size_t)bh * Lc + q) * Dc;
        *(float4*)(Or + tx * 4)      = make_float4(acc[i][0], acc[i][1], acc[i][2], acc[i][3]);
        *(float4*)(Or + 64 + tx * 4) = make_float4(acc[i][4], acc[i][5], acc[i][6], acc[i][7]);
    }
}

// ---------------------------------------------------------------------------
extern "C" void kernel_launch(void* const* d_in, const int* in_sizes, int n_in,
                              void* d_out, int out_size, void* d_ws, size_t ws_size,
                              hipStream_t stream)
{
    const float* Q  = (const float*)d_in[0];
    const float* K  = (const float*)d_in[1];
    const float* V  = (const float*)d_in[2];
    const float* A  = (const float*)d_in[3];
    const float* Ds = (const float*)d_in[4];
    const float* wA = (const float*)d_in[5];
    const float* wD = (const float*)d_in[6];

    float* out  = (float*)d_out;            // (B,H,L,D)
    float* attn = out + OUT_ELEMS;          // (B,H,L,L)

    hipLaunchKernelGGL(k_scores, dim3(Lc / 128, Lc / 128, BHc), dim3(256), 0, stream,
                       Q, K, A, Ds, wA, wD, attn);
    hipLaunchKernelGGL(k_softmax, dim3(BHc * Lc), dim3(256), 0, stream, attn);
    hipLaunchKernelGGL(k_pv, dim3(Lc / 128, BHc), dim3(256), 0, stream, attn, V, out);
}